// Round 1
// baseline (276.932 us; speedup 1.0000x reference)
//
#include <hip/hip_runtime.h>
#include <cstdint>

#define HB 8
#define CM 128
#define NHEAD 8
#define NPT 8
#define DHD 16
#define HS 64
#define WS 64
#define LTOT 4096
#define NQA 192   // fused off(128) + attn(64)
#define QAP 196   // qaT LDS pitch (floats): 196%32=4 -> 4-way max on float4 reads; 32*196*4=25088 B
#define LFP 132   // gemm_val transpose pitch (floats): 132%32=4 spreads banks

typedef float floatx4 __attribute__((ext_vector_type(4)));
typedef short bf16x8 __attribute__((ext_vector_type(8)));

__device__ __forceinline__ unsigned short f2bf_rne(float x) {
  unsigned u = __float_as_uint(x);
  return (unsigned short)((u + 0x7FFFu + ((u >> 16) & 1)) >> 16);
}
__device__ __forceinline__ void split_bf(float x, unsigned short& h, unsigned short& l) {
  unsigned u = __float_as_uint(x);
  h = (unsigned short)(u >> 16);
  float r = x - __uint_as_float(u & 0xFFFF0000u);
  l = (unsigned short)(__float_as_uint(r) >> 16);
}
__device__ __forceinline__ float fast_tanh(float x) {
  float e = __expf(2.0f * x);
  return 1.0f - 2.0f / (e + 1.0f);
}
// unpack uint4 (8 bf16) -> 2x floatx4, fused multiply-accumulate by scalar wc
__device__ __forceinline__ void bf8_fma(floatx4& oa, floatx4& ob, const uint4 r, const float wc) {
  floatx4 va = {__uint_as_float(r.x << 16), __uint_as_float(r.x & 0xFFFF0000u),
                __uint_as_float(r.y << 16), __uint_as_float(r.y & 0xFFFF0000u)};
  floatx4 vb = {__uint_as_float(r.z << 16), __uint_as_float(r.z & 0xFFFF0000u),
                __uint_as_float(r.w << 16), __uint_as_float(r.w & 0xFFFF0000u)};
  oa += va * wc;
  ob += vb * wc;
}

// Weight prep -> bf16 hi/lo fragment layout: element (n,k) at (k>>3)*Nn*8 + n*8 + (k&7).
__global__ __launch_bounds__(256) void prep(const float* __restrict__ Wv,
                                            const float* __restrict__ Wo,
                                            const float* __restrict__ Wa,
                                            const float* __restrict__ Ww,
                                            const float* __restrict__ bo,
                                            const float* __restrict__ ba,
                                            unsigned short* __restrict__ wf_val,
                                            unsigned short* __restrict__ wf_qa,
                                            unsigned short* __restrict__ wf_out,
                                            float* __restrict__ bias_qa) {
  const int gid = blockIdx.x * 256 + threadIdx.x;  // 14336 = 32 k4 * 448 n
  const int k4 = gid / 448;
  const int ng = gid - k4 * 448;

  const float* src;
  unsigned short* dst;
  int Nsrc, Nn, nd, n;
  if (ng < 128) {        src = Wv; dst = wf_val; Nsrc = 128; Nn = 128; n = ng;        nd = n; }
  else if (ng < 256) {   src = Wo; dst = wf_qa;  Nsrc = 128; Nn = 192; n = ng - 128;  nd = n; }
  else if (ng < 320) {   src = Wa; dst = wf_qa;  Nsrc = 64;  Nn = 192; n = ng - 256;  nd = n + 128; }
  else {                 src = Ww; dst = wf_out; Nsrc = 128; Nn = 128; n = ng - 320;  nd = n; }

  ushort4 hi, lo;
  split_bf(src[(k4 * 4 + 0) * Nsrc + n], hi.x, lo.x);
  split_bf(src[(k4 * 4 + 1) * Nsrc + n], hi.y, lo.y);
  split_bf(src[(k4 * 4 + 2) * Nsrc + n], hi.z, lo.z);
  split_bf(src[(k4 * 4 + 3) * Nsrc + n], hi.w, lo.w);
  const int off = (k4 >> 1) * Nn * 8 + nd * 8 + (k4 & 1) * 4;
  *(ushort4*)(dst + off) = hi;
  *(ushort4*)(dst + Nn * 128 + off) = lo;

  if (gid < 128) bias_qa[gid] = bo[gid];
  else if (gid < 192) bias_qa[gid] = ba[gid - 128];
}

// K1: value projection. Tile 64 m x 128 n, 256 thr (4 waves, wave = 32m x 64n).
// 3-term bf16 split. Epilogue: LDS transpose -> COALESCED uint4 bf16 stores.
__global__ __launch_bounds__(256, 4) void gemm_val(const float* __restrict__ nbr,
                                                   const unsigned short* __restrict__ WF,
                                                   const float* __restrict__ bias,
                                                   unsigned short* __restrict__ value) {
  __shared__ __align__(16) char smem[33792];   // staging 32768; transpose 64*132*4=33792
  unsigned short* AB = (unsigned short*)smem;  // hi [64][128]; lo at +8192 us
  const int t = threadIdx.x;
  const int ml0 = blockIdx.x * 64;
  const int b = blockIdx.y;

  {
    const float* src = nbr + (size_t)b * CM * LTOT + ml0;
    const int x = t & 63, kq = t >> 6;
#pragma unroll
    for (int i = 0; i < 8; i++) {
      const int kb = kq * 4 + i * 16;
      ushort4 hi, lo;
      split_bf(src[(size_t)(kb + 0) * LTOT + x], hi.x, lo.x);
      split_bf(src[(size_t)(kb + 1) * LTOT + x], hi.y, lo.y);
      split_bf(src[(size_t)(kb + 2) * LTOT + x], hi.z, lo.z);
      split_bf(src[(size_t)(kb + 3) * LTOT + x], hi.w, lo.w);
      const int off = x * 128 + (((kb >> 3) ^ (x & 15)) << 3) + (kb & 7);
      *(ushort4*)(AB + off) = hi;
      *(ushort4*)(AB + 8192 + off) = lo;
    }
  }
  __syncthreads();

  const int w = t >> 6, lane = t & 63;
  const int wm = (w >> 1) * 32, wn = (w & 1) * 64;
  const int nl = lane & 15, q = lane >> 4;

  floatx4 acc[2][4];
#pragma unroll
  for (int mt = 0; mt < 2; mt++)
#pragma unroll
    for (int j = 0; j < 4; j++) acc[mt][j] = {0.0f, 0.0f, 0.0f, 0.0f};

#pragma unroll
  for (int K0 = 0; K0 < 4; K0++) {
    bf16x8 ah[2], al[2];
#pragma unroll
    for (int mt = 0; mt < 2; mt++) {
      const int m = wm + mt * 16 + nl;
      const int off = m * 128 + (((K0 * 4 + q) ^ (m & 15)) << 3);
      ah[mt] = *(bf16x8*)(AB + off);
      al[mt] = *(bf16x8*)(AB + 8192 + off);
    }
#pragma unroll
    for (int j = 0; j < 4; j++) {
      const size_t o = (size_t)(K0 * 4 + q) * CM * 8 + (wn + j * 16 + nl) * 8;
      const bf16x8 wh = *(const bf16x8*)(WF + o);
      const bf16x8 wl = *(const bf16x8*)(WF + (size_t)CM * 128 + o);
#pragma unroll
      for (int mt = 0; mt < 2; mt++) {
        acc[mt][j] = __builtin_amdgcn_mfma_f32_16x16x32_bf16(al[mt], wh, acc[mt][j], 0, 0, 0);
        acc[mt][j] = __builtin_amdgcn_mfma_f32_16x16x32_bf16(ah[mt], wl, acc[mt][j], 0, 0, 0);
        acc[mt][j] = __builtin_amdgcn_mfma_f32_16x16x32_bf16(ah[mt], wh, acc[mt][j], 0, 0, 0);
      }
    }
  }

  // ---- epilogue: acc -> LDS [64 l][132] fp32 -> packed bf16 uint4 coalesced stores ----
  __syncthreads();  // AB dead
  float* LF = (float*)smem;
#pragma unroll
  for (int j = 0; j < 4; j++) {
    const int gc = wn + j * 16 + nl;
    const float bv = bias[gc];
#pragma unroll
    for (int mt = 0; mt < 2; mt++)
#pragma unroll
      for (int r = 0; r < 4; r++)
        LF[(wm + mt * 16 + q * 4 + r) * LFP + gc] = acc[mt][j][r] + bv;
  }
  __syncthreads();
  // 1024 uint4 chunks: c = h(3b) | l(6b) | half(1b); wave writes contiguous 1 KB per h
#pragma unroll
  for (int i = 0; i < 4; i++) {
    const int c = t + i * 256;
    const int h = c >> 7, rem = c & 127, l = rem >> 1, half = rem & 1;
    const float* sp = LF + l * LFP + h * 16 + half * 8;
    uint4 st;
    st.x = ((unsigned)f2bf_rne(sp[1]) << 16) | f2bf_rne(sp[0]);
    st.y = ((unsigned)f2bf_rne(sp[3]) << 16) | f2bf_rne(sp[2]);
    st.z = ((unsigned)f2bf_rne(sp[5]) << 16) | f2bf_rne(sp[4]);
    st.w = ((unsigned)f2bf_rne(sp[7]) << 16) | f2bf_rne(sp[6]);
    *(uint4*)(value + ((size_t)(b * NHEAD + h) * LTOT + ml0 + l) * DHD + half * 8) = st;
  }
}

// K2 (rewritten): per 32-l tile: stage ext -> qa GEMM -> sampling params in REGISTERS ->
// full-dh gather (thread = one (ll,h), 32B/corner via 2x uint4) -> out GEMM.
// LDS phases overlap at offset 0: AB(16K) / qaT(25088) / FR(8K) -> 25088 B total,
// 5-6 blocks/CU (was 4 @ 40960). No WXY/WA LDS round-trip: the param producer thread
// IS the gather consumer thread under the (ll=t>>3, h=t&7) mapping.
__global__ __launch_bounds__(256, 5) void samp(const float* __restrict__ ext,
                                               const unsigned short* __restrict__ value,
                                               const unsigned short* __restrict__ wf_qa,
                                               const unsigned short* __restrict__ wf_out,
                                               const float* __restrict__ bias_qa,
                                               const float* __restrict__ b_out,
                                               float* __restrict__ out) {
  __shared__ __align__(16) char smem[25088];
  unsigned short* AB = (unsigned short*)smem;  // [32][128] hi; lo at +4096 us (16384 B)
  float* qaT = (float*)smem;                   // [32][QAP] = 25088 B (after AB dead)
  unsigned short* FR = (unsigned short*)smem;  // [32][128] bf16 = 8192 B (after qaT dead)

  const int t = threadIdx.x;
  const int b = blockIdx.x & 7;                // XCD affinity
  const int ml0 = (blockIdx.x >> 3) * 32;
  const int w = t >> 6, lane = t & 63;
  const int nl = lane & 15, q = lane >> 4;

  // ---- stage ext 32-l tile (fp32 -> bf16 hi/lo, swizzled) ----
  {
    const float* src = ext + (size_t)b * CM * LTOT + ml0;
    const int x = t & 31, kq = t >> 5;  // kq 0..7
#pragma unroll
    for (int i = 0; i < 4; i++) {
      const int kb = i * 32 + kq * 4;
      ushort4 hi, lo;
      split_bf(src[(size_t)(kb + 0) * LTOT + x], hi.x, lo.x);
      split_bf(src[(size_t)(kb + 1) * LTOT + x], hi.y, lo.y);
      split_bf(src[(size_t)(kb + 2) * LTOT + x], hi.z, lo.z);
      split_bf(src[(size_t)(kb + 3) * LTOT + x], hi.w, lo.w);
      const int off = x * 128 + (((kb >> 3) ^ (x & 15)) << 3) + (kb & 7);
      *(ushort4*)(AB + off) = hi;
      *(ushort4*)(AB + 4096 + off) = lo;
    }
  }
  __syncthreads();

  // ---- qa GEMM: 32m x 192n, 4 waves, wave = 16m x 96n; result -> qaT (LDS, overlaps AB) ----
  {
    const int wm = (w & 1) * 16;
    const int wn = (w >> 1) * 96;
    floatx4 acc[6];
#pragma unroll
    for (int j = 0; j < 6; j++) acc[j] = {0.0f, 0.0f, 0.0f, 0.0f};
#pragma unroll
    for (int K0 = 0; K0 < 4; K0++) {
      const int m = wm + nl;
      const int off = m * 128 + (((K0 * 4 + q) ^ (m & 15)) << 3);
      const bf16x8 ah = *(bf16x8*)(AB + off);
      const bf16x8 al = *(bf16x8*)(AB + 4096 + off);
#pragma unroll
      for (int j = 0; j < 6; j++) {
        const size_t o = (size_t)(K0 * 4 + q) * NQA * 8 + (wn + j * 16 + nl) * 8;
        const bf16x8 wh = *(const bf16x8*)(wf_qa + o);
        const bf16x8 wl = *(const bf16x8*)(wf_qa + (size_t)NQA * 128 + o);
        acc[j] = __builtin_amdgcn_mfma_f32_16x16x32_bf16(al, wh, acc[j], 0, 0, 0);
        acc[j] = __builtin_amdgcn_mfma_f32_16x16x32_bf16(ah, wl, acc[j], 0, 0, 0);
        acc[j] = __builtin_amdgcn_mfma_f32_16x16x32_bf16(ah, wh, acc[j], 0, 0, 0);
      }
    }
    __syncthreads();  // all AB reads done -> qaT may overwrite
#pragma unroll
    for (int j = 0; j < 6; j++) {
      const int n = wn + j * 16 + nl;
      const float bv = bias_qa[n];
#pragma unroll
      for (int r = 0; r < 4; r++)
        qaT[(wm + q * 4 + r) * QAP + n] = acc[j][r] + bv;
    }
  }
  __syncthreads();

  // ---- sampling params -> REGISTERS; thread t = (ll = t>>3, h = t&7), same as gather ----
  float px[8], py[8], aw[8];
  const int ll = t >> 3, h = t & 7;
  {
    const float* qrow = qaT + ll * QAP;
    float4 of[4];
#pragma unroll
    for (int j = 0; j < 4; j++) of[j] = *(const float4*)(qrow + h * 16 + j * 4);
    const float4 lga = *(const float4*)(qrow + 128 + h * 8);
    const float4 lgb = *(const float4*)(qrow + 128 + h * 8 + 4);
    const float lg[8] = {lga.x, lga.y, lga.z, lga.w, lgb.x, lgb.y, lgb.z, lgb.w};
    float m = lg[0];
#pragma unroll
    for (int p = 1; p < 8; p++) m = fmaxf(m, lg[p]);
    float e[8], s = 0.0f;
#pragma unroll
    for (int p = 0; p < 8; p++) { e[p] = __expf(lg[p] - m); s += e[p]; }
    const float inv = 1.0f / s;
    const int l = ml0 + ll;
    const float xf = (float)(l & (WS - 1));
    const float yf = (float)(l >> 6);
#pragma unroll
    for (int p = 0; p < 8; p++) {
      const float ox = (p & 1) ? of[p >> 1].z : of[p >> 1].x;
      const float oy = (p & 1) ? of[p >> 1].w : of[p >> 1].y;
      px[p] = xf + 10.0f * fast_tanh(ox);
      py[p] = yf + 10.0f * fast_tanh(oy);
      aw[p] = e[p] * inv;
    }
  }
  __syncthreads();  // qaT dead -> FR may be written

  // ---- gather: thread owns full dh=16 of one (ll,h); 32B per corner (2x uint4) ----
  {
    const unsigned hb = (unsigned)(b * NHEAD + h) * LTOT * DHD;  // us offset of head plane
    floatx4 o0 = {0.f, 0.f, 0.f, 0.f}, o1 = o0, o2 = o0, o3 = o0;
#pragma unroll
    for (int p = 0; p < 8; p++) {
      const float x0f = floorf(px[p]), y0f = floorf(py[p]);
      const float fx = px[p] - x0f, fy = py[p] - y0f;
      const int ix = (int)x0f, iy = (int)y0f;
      const float a = aw[p];
      float wc[4];
      unsigned adr[4];
#pragma unroll
      for (int c = 0; c < 4; c++) {
        const int cdx = c & 1, cdy = c >> 1;
        const int jx = ix + cdx, jy = iy + cdy;
        const float wx = cdx ? fx : 1.0f - fx;
        const float wy = cdy ? fy : 1.0f - fy;
        const bool valid = ((unsigned)jx < WS) & ((unsigned)jy < HS);
        wc[c] = valid ? a * wx * wy : 0.0f;
        const int cx = min(max(jx, 0), WS - 1);
        const int cy = min(max(jy, 0), HS - 1);
        adr[c] = hb + (unsigned)((cy << 6) + cx) * DHD;
      }
      uint4 r0[4], r1[4];
#pragma unroll
      for (int c = 0; c < 4; c++) {
        r0[c] = *(const uint4*)(value + adr[c]);
        r1[c] = *(const uint4*)(value + adr[c] + 8);
      }
#pragma unroll
      for (int c = 0; c < 4; c++) {
        bf8_fma(o0, o1, r0[c], wc[c]);
        bf8_fma(o2, o3, r1[c], wc[c]);
      }
    }
    // write FR: two swizzled uint4 (groups g = h*2+d8 hold channels k = g*8..g*8+7)
    const int llm = ll & 15;
    {
      const int off = ll * 128 + (((h * 2 + 0) ^ llm) << 3);
      uint4 st;
      st.x = ((unsigned)f2bf_rne(o0[1]) << 16) | f2bf_rne(o0[0]);
      st.y = ((unsigned)f2bf_rne(o0[3]) << 16) | f2bf_rne(o0[2]);
      st.z = ((unsigned)f2bf_rne(o1[1]) << 16) | f2bf_rne(o1[0]);
      st.w = ((unsigned)f2bf_rne(o1[3]) << 16) | f2bf_rne(o1[2]);
      *(uint4*)(FR + off) = st;
    }
    {
      const int off = ll * 128 + (((h * 2 + 1) ^ llm) << 3);
      uint4 st;
      st.x = ((unsigned)f2bf_rne(o2[1]) << 16) | f2bf_rne(o2[0]);
      st.y = ((unsigned)f2bf_rne(o2[3]) << 16) | f2bf_rne(o2[2]);
      st.z = ((unsigned)f2bf_rne(o3[1]) << 16) | f2bf_rne(o3[0]);
      st.w = ((unsigned)f2bf_rne(o3[3]) << 16) | f2bf_rne(o3[2]);
      *(uint4*)(FR + off) = st;
    }
  }
  __syncthreads();

  // ---- out GEMM: 32m x 128n, 4 waves, wave = 16m x 64n; direct float4 stores ----
  {
    const int wm = (w & 1) * 16;
    const int wn = (w >> 1) * 64;
    floatx4 acc[4];
#pragma unroll
    for (int j = 0; j < 4; j++) acc[j] = {0.0f, 0.0f, 0.0f, 0.0f};
#pragma unroll
    for (int K0 = 0; K0 < 4; K0++) {
      const int m = wm + nl;
      const int off = m * 128 + (((K0 * 4 + q) ^ (m & 15)) << 3);
      const bf16x8 ah = *(bf16x8*)(FR + off);
#pragma unroll
      for (int j = 0; j < 4; j++) {
        const int n = wn + j * 16 + nl;
        const size_t o = (size_t)(K0 * 4 + q) * CM * 8 + n * 8;
        const bf16x8 wh = *(const bf16x8*)(wf_out + o);
        const bf16x8 wl = *(const bf16x8*)(wf_out + (size_t)CM * 128 + o);
        acc[j] = __builtin_amdgcn_mfma_f32_16x16x32_bf16(ah, wl, acc[j], 0, 0, 0);
        acc[j] = __builtin_amdgcn_mfma_f32_16x16x32_bf16(ah, wh, acc[j], 0, 0, 0);
      }
    }
    // C/D: col=nl -> n, rows q*4+r -> m (contiguous in bchw) => float4 store
#pragma unroll
    for (int j = 0; j < 4; j++) {
      const int gc = wn + j * 16 + nl;
      const float bv = b_out[gc];
      float4 st = {acc[j][0] + bv, acc[j][1] + bv, acc[j][2] + bv, acc[j][3] + bv};
      *(float4*)(out + ((size_t)b * CM + gc) * LTOT + ml0 + wm + q * 4) = st;
    }
  }
}

extern "C" void kernel_launch(void* const* d_in, const int* in_sizes, int n_in,
                              void* d_out, int out_size, void* d_ws, size_t ws_size,
                              hipStream_t stream) {
  const float* nbr    = (const float*)d_in[0];
  const float* ext    = (const float*)d_in[1];
  const float* W_val  = (const float*)d_in[2];
  const float* b_val  = (const float*)d_in[3];
  const float* W_off  = (const float*)d_in[4];
  const float* b_off  = (const float*)d_in[5];
  const float* W_attn = (const float*)d_in[6];
  const float* b_attn = (const float*)d_in[7];
  const float* W_out  = (const float*)d_in[8];
  const float* b_out  = (const float*)d_in[9];
  float* out = (float*)d_out;

  unsigned short* value = (unsigned short*)d_ws;             // 8.39 MB bf16 [b][h][l][16]
  unsigned short* wf_val = value + (size_t)HB * NHEAD * LTOT * DHD;  // 64 KB
  unsigned short* wf_qa  = wf_val + 128 * 128 * 2;           // 96 KB
  unsigned short* wf_out = wf_qa + 192 * 128 * 2;            // 64 KB
  float* bias_qa = (float*)(wf_out + 128 * 128 * 2);         // 768 B

  prep<<<56, 256, 0, stream>>>(W_val, W_off, W_attn, W_out, b_off, b_attn,
                               wf_val, wf_qa, wf_out, bias_qa);
  gemm_val<<<dim3(64, HB), 256, 0, stream>>>(nbr, wf_val, b_val, value);
  samp<<<dim3(128 * HB), 256, 0, stream>>>(ext, value, wf_qa, wf_out, bias_qa, b_out, out);
}

// Round 2
// 232.077 us; speedup vs baseline: 1.1933x; 1.1933x over previous
//
#include <hip/hip_runtime.h>
#include <cstdint>

#define HB 8
#define CM 128
#define NHEAD 8
#define NPT 8
#define DHD 16
#define HS 64
#define WS 64
#define LTOT 4096
#define NQA 192   // fused off(128) + attn(64)
#define QAP 196   // qaT LDS pitch (floats): 196%32=4 -> 4-way max on float4 reads; 32*196*4=25088 B
#define LFP 132   // gemm_val transpose pitch (floats): 132%32=4 spreads banks

typedef float floatx4 __attribute__((ext_vector_type(4)));
typedef short bf16x8 __attribute__((ext_vector_type(8)));

__device__ __forceinline__ unsigned short f2bf_rne(float x) {
  unsigned u = __float_as_uint(x);
  return (unsigned short)((u + 0x7FFFu + ((u >> 16) & 1)) >> 16);
}
__device__ __forceinline__ void split_bf(float x, unsigned short& h, unsigned short& l) {
  unsigned u = __float_as_uint(x);
  h = (unsigned short)(u >> 16);
  float r = x - __uint_as_float(u & 0xFFFF0000u);
  l = (unsigned short)(__float_as_uint(r) >> 16);
}
__device__ __forceinline__ float fast_tanh(float x) {
  float e = __expf(2.0f * x);
  return 1.0f - 2.0f / (e + 1.0f);
}
// unpack uint4 (8 bf16) -> 2x floatx4, fused multiply-accumulate by scalar wc
__device__ __forceinline__ void bf8_fma(floatx4& oa, floatx4& ob, const uint4 r, const float wc) {
  floatx4 va = {__uint_as_float(r.x << 16), __uint_as_float(r.x & 0xFFFF0000u),
                __uint_as_float(r.y << 16), __uint_as_float(r.y & 0xFFFF0000u)};
  floatx4 vb = {__uint_as_float(r.z << 16), __uint_as_float(r.z & 0xFFFF0000u),
                __uint_as_float(r.w << 16), __uint_as_float(r.w & 0xFFFF0000u)};
  oa += va * wc;
  ob += vb * wc;
}

// Weight prep -> bf16 hi/lo fragment layout: element (n,k) at (k>>3)*Nn*8 + n*8 + (k&7).
__global__ __launch_bounds__(256) void prep(const float* __restrict__ Wv,
                                            const float* __restrict__ Wo,
                                            const float* __restrict__ Wa,
                                            const float* __restrict__ Ww,
                                            const float* __restrict__ bo,
                                            const float* __restrict__ ba,
                                            unsigned short* __restrict__ wf_val,
                                            unsigned short* __restrict__ wf_qa,
                                            unsigned short* __restrict__ wf_out,
                                            float* __restrict__ bias_qa) {
  const int gid = blockIdx.x * 256 + threadIdx.x;  // 14336 = 32 k4 * 448 n
  const int k4 = gid / 448;
  const int ng = gid - k4 * 448;

  const float* src;
  unsigned short* dst;
  int Nsrc, Nn, nd, n;
  if (ng < 128) {        src = Wv; dst = wf_val; Nsrc = 128; Nn = 128; n = ng;        nd = n; }
  else if (ng < 256) {   src = Wo; dst = wf_qa;  Nsrc = 128; Nn = 192; n = ng - 128;  nd = n; }
  else if (ng < 320) {   src = Wa; dst = wf_qa;  Nsrc = 64;  Nn = 192; n = ng - 256;  nd = n + 128; }
  else {                 src = Ww; dst = wf_out; Nsrc = 128; Nn = 128; n = ng - 320;  nd = n; }

  ushort4 hi, lo;
  split_bf(src[(k4 * 4 + 0) * Nsrc + n], hi.x, lo.x);
  split_bf(src[(k4 * 4 + 1) * Nsrc + n], hi.y, lo.y);
  split_bf(src[(k4 * 4 + 2) * Nsrc + n], hi.z, lo.z);
  split_bf(src[(k4 * 4 + 3) * Nsrc + n], hi.w, lo.w);
  const int off = (k4 >> 1) * Nn * 8 + nd * 8 + (k4 & 1) * 4;
  *(ushort4*)(dst + off) = hi;
  *(ushort4*)(dst + Nn * 128 + off) = lo;

  if (gid < 128) bias_qa[gid] = bo[gid];
  else if (gid < 192) bias_qa[gid] = ba[gid - 128];
}

// K1: value projection. Tile 64 m x 128 n, 256 thr (4 waves, wave = 32m x 64n).
// 3-term bf16 split. Epilogue: LDS transpose -> COALESCED uint4 bf16 stores.
__global__ __launch_bounds__(256, 4) void gemm_val(const float* __restrict__ nbr,
                                                   const unsigned short* __restrict__ WF,
                                                   const float* __restrict__ bias,
                                                   unsigned short* __restrict__ value) {
  __shared__ __align__(16) char smem[33792];   // staging 32768; transpose 64*132*4=33792
  unsigned short* AB = (unsigned short*)smem;  // hi [64][128]; lo at +8192 us
  const int t = threadIdx.x;
  const int ml0 = blockIdx.x * 64;
  const int b = blockIdx.y;

  {
    const float* src = nbr + (size_t)b * CM * LTOT + ml0;
    const int x = t & 63, kq = t >> 6;
#pragma unroll
    for (int i = 0; i < 8; i++) {
      const int kb = kq * 4 + i * 16;
      ushort4 hi, lo;
      split_bf(src[(size_t)(kb + 0) * LTOT + x], hi.x, lo.x);
      split_bf(src[(size_t)(kb + 1) * LTOT + x], hi.y, lo.y);
      split_bf(src[(size_t)(kb + 2) * LTOT + x], hi.z, lo.z);
      split_bf(src[(size_t)(kb + 3) * LTOT + x], hi.w, lo.w);
      const int off = x * 128 + (((kb >> 3) ^ (x & 15)) << 3) + (kb & 7);
      *(ushort4*)(AB + off) = hi;
      *(ushort4*)(AB + 8192 + off) = lo;
    }
  }
  __syncthreads();

  const int w = t >> 6, lane = t & 63;
  const int wm = (w >> 1) * 32, wn = (w & 1) * 64;
  const int nl = lane & 15, q = lane >> 4;

  floatx4 acc[2][4];
#pragma unroll
  for (int mt = 0; mt < 2; mt++)
#pragma unroll
    for (int j = 0; j < 4; j++) acc[mt][j] = {0.0f, 0.0f, 0.0f, 0.0f};

#pragma unroll
  for (int K0 = 0; K0 < 4; K0++) {
    bf16x8 ah[2], al[2];
#pragma unroll
    for (int mt = 0; mt < 2; mt++) {
      const int m = wm + mt * 16 + nl;
      const int off = m * 128 + (((K0 * 4 + q) ^ (m & 15)) << 3);
      ah[mt] = *(bf16x8*)(AB + off);
      al[mt] = *(bf16x8*)(AB + 8192 + off);
    }
#pragma unroll
    for (int j = 0; j < 4; j++) {
      const size_t o = (size_t)(K0 * 4 + q) * CM * 8 + (wn + j * 16 + nl) * 8;
      const bf16x8 wh = *(const bf16x8*)(WF + o);
      const bf16x8 wl = *(const bf16x8*)(WF + (size_t)CM * 128 + o);
#pragma unroll
      for (int mt = 0; mt < 2; mt++) {
        acc[mt][j] = __builtin_amdgcn_mfma_f32_16x16x32_bf16(al[mt], wh, acc[mt][j], 0, 0, 0);
        acc[mt][j] = __builtin_amdgcn_mfma_f32_16x16x32_bf16(ah[mt], wl, acc[mt][j], 0, 0, 0);
        acc[mt][j] = __builtin_amdgcn_mfma_f32_16x16x32_bf16(ah[mt], wh, acc[mt][j], 0, 0, 0);
      }
    }
  }

  // ---- epilogue: acc -> LDS [64 l][132] fp32 -> packed bf16 uint4 coalesced stores ----
  __syncthreads();  // AB dead
  float* LF = (float*)smem;
#pragma unroll
  for (int j = 0; j < 4; j++) {
    const int gc = wn + j * 16 + nl;
    const float bv = bias[gc];
#pragma unroll
    for (int mt = 0; mt < 2; mt++)
#pragma unroll
      for (int r = 0; r < 4; r++)
        LF[(wm + mt * 16 + q * 4 + r) * LFP + gc] = acc[mt][j][r] + bv;
  }
  __syncthreads();
  // 1024 uint4 chunks: c = h(3b) | l(6b) | half(1b); wave writes contiguous 1 KB per h
#pragma unroll
  for (int i = 0; i < 4; i++) {
    const int c = t + i * 256;
    const int h = c >> 7, rem = c & 127, l = rem >> 1, half = rem & 1;
    const float* sp = LF + l * LFP + h * 16 + half * 8;
    uint4 st;
    st.x = ((unsigned)f2bf_rne(sp[1]) << 16) | f2bf_rne(sp[0]);
    st.y = ((unsigned)f2bf_rne(sp[3]) << 16) | f2bf_rne(sp[2]);
    st.z = ((unsigned)f2bf_rne(sp[5]) << 16) | f2bf_rne(sp[4]);
    st.w = ((unsigned)f2bf_rne(sp[7]) << 16) | f2bf_rne(sp[6]);
    *(uint4*)(value + ((size_t)(b * NHEAD + h) * LTOT + ml0 + l) * DHD + half * 8) = st;
  }
}

// K2: per 32-l tile: stage ext -> qa GEMM -> sampling params in REGISTERS ->
// full-dh gather (thread = one (ll,h), 32B/corner via 2x uint4) -> out GEMM.
// LDS phases overlap at offset 0: AB(16K) / qaT(25088) / FR(8K) -> 25088 B total.
// launch_bounds(256,4): (256,5) capped VGPR at ~102 -> compiler hit 48 with SPILLS
// (-> 446 MB scratch HBM traffic, 2x regression). 128-VGPR cap: no spills; LDS still
// allows 6 blocks/CU so occupancy lands VGPR-limited ~5.
__global__ __launch_bounds__(256, 4) void samp(const float* __restrict__ ext,
                                               const unsigned short* __restrict__ value,
                                               const unsigned short* __restrict__ wf_qa,
                                               const unsigned short* __restrict__ wf_out,
                                               const float* __restrict__ bias_qa,
                                               const float* __restrict__ b_out,
                                               float* __restrict__ out) {
  __shared__ __align__(16) char smem[25088];
  unsigned short* AB = (unsigned short*)smem;  // [32][128] hi; lo at +4096 us (16384 B)
  float* qaT = (float*)smem;                   // [32][QAP] = 25088 B (after AB dead)
  unsigned short* FR = (unsigned short*)smem;  // [32][128] bf16 = 8192 B (after qaT dead)

  const int t = threadIdx.x;
  const int b = blockIdx.x & 7;                // XCD affinity
  const int ml0 = (blockIdx.x >> 3) * 32;
  const int w = t >> 6, lane = t & 63;
  const int nl = lane & 15, q = lane >> 4;

  // ---- stage ext 32-l tile (fp32 -> bf16 hi/lo, swizzled) ----
  {
    const float* src = ext + (size_t)b * CM * LTOT + ml0;
    const int x = t & 31, kq = t >> 5;  // kq 0..7
#pragma unroll
    for (int i = 0; i < 4; i++) {
      const int kb = i * 32 + kq * 4;
      ushort4 hi, lo;
      split_bf(src[(size_t)(kb + 0) * LTOT + x], hi.x, lo.x);
      split_bf(src[(size_t)(kb + 1) * LTOT + x], hi.y, lo.y);
      split_bf(src[(size_t)(kb + 2) * LTOT + x], hi.z, lo.z);
      split_bf(src[(size_t)(kb + 3) * LTOT + x], hi.w, lo.w);
      const int off = x * 128 + (((kb >> 3) ^ (x & 15)) << 3) + (kb & 7);
      *(ushort4*)(AB + off) = hi;
      *(ushort4*)(AB + 4096 + off) = lo;
    }
  }
  __syncthreads();

  // ---- qa GEMM: 32m x 192n, 4 waves, wave = 16m x 96n; result -> qaT (LDS, overlaps AB) ----
  {
    const int wm = (w & 1) * 16;
    const int wn = (w >> 1) * 96;
    floatx4 acc[6];
#pragma unroll
    for (int j = 0; j < 6; j++) acc[j] = {0.0f, 0.0f, 0.0f, 0.0f};
#pragma unroll
    for (int K0 = 0; K0 < 4; K0++) {
      const int m = wm + nl;
      const int off = m * 128 + (((K0 * 4 + q) ^ (m & 15)) << 3);
      const bf16x8 ah = *(bf16x8*)(AB + off);
      const bf16x8 al = *(bf16x8*)(AB + 4096 + off);
#pragma unroll
      for (int j = 0; j < 6; j++) {
        const size_t o = (size_t)(K0 * 4 + q) * NQA * 8 + (wn + j * 16 + nl) * 8;
        const bf16x8 wh = *(const bf16x8*)(wf_qa + o);
        const bf16x8 wl = *(const bf16x8*)(wf_qa + (size_t)NQA * 128 + o);
        acc[j] = __builtin_amdgcn_mfma_f32_16x16x32_bf16(al, wh, acc[j], 0, 0, 0);
        acc[j] = __builtin_amdgcn_mfma_f32_16x16x32_bf16(ah, wl, acc[j], 0, 0, 0);
        acc[j] = __builtin_amdgcn_mfma_f32_16x16x32_bf16(ah, wh, acc[j], 0, 0, 0);
      }
    }
    __syncthreads();  // all AB reads done -> qaT may overwrite
#pragma unroll
    for (int j = 0; j < 6; j++) {
      const int n = wn + j * 16 + nl;
      const float bv = bias_qa[n];
#pragma unroll
      for (int r = 0; r < 4; r++)
        qaT[(wm + q * 4 + r) * QAP + n] = acc[j][r] + bv;
    }
  }
  __syncthreads();

  // ---- sampling params -> REGISTERS; thread t = (ll = t>>3, h = t&7), same as gather ----
  float px[8], py[8], aw[8];
  const int ll = t >> 3, h = t & 7;
  {
    const float* qrow = qaT + ll * QAP;
    float4 of[4];
#pragma unroll
    for (int j = 0; j < 4; j++) of[j] = *(const float4*)(qrow + h * 16 + j * 4);
    const float4 lga = *(const float4*)(qrow + 128 + h * 8);
    const float4 lgb = *(const float4*)(qrow + 128 + h * 8 + 4);
    const float lg[8] = {lga.x, lga.y, lga.z, lga.w, lgb.x, lgb.y, lgb.z, lgb.w};
    float m = lg[0];
#pragma unroll
    for (int p = 1; p < 8; p++) m = fmaxf(m, lg[p]);
    float e[8], s = 0.0f;
#pragma unroll
    for (int p = 0; p < 8; p++) { e[p] = __expf(lg[p] - m); s += e[p]; }
    const float inv = 1.0f / s;
    const int l = ml0 + ll;
    const float xf = (float)(l & (WS - 1));
    const float yf = (float)(l >> 6);
#pragma unroll
    for (int p = 0; p < 8; p++) {
      const float ox = (p & 1) ? of[p >> 1].z : of[p >> 1].x;
      const float oy = (p & 1) ? of[p >> 1].w : of[p >> 1].y;
      px[p] = xf + 10.0f * fast_tanh(ox);
      py[p] = yf + 10.0f * fast_tanh(oy);
      aw[p] = e[p] * inv;
    }
  }
  __syncthreads();  // qaT dead -> FR may be written

  // ---- gather: thread owns full dh=16 of one (ll,h); 32B per corner (2x uint4) ----
  {
    const unsigned hb = (unsigned)(b * NHEAD + h) * LTOT * DHD;  // us offset of head plane
    floatx4 o0 = {0.f, 0.f, 0.f, 0.f}, o1 = o0, o2 = o0, o3 = o0;
#pragma unroll
    for (int p = 0; p < 8; p++) {
      const float x0f = floorf(px[p]), y0f = floorf(py[p]);
      const float fx = px[p] - x0f, fy = py[p] - y0f;
      const int ix = (int)x0f, iy = (int)y0f;
      const float a = aw[p];
      float wc[4];
      unsigned adr[4];
#pragma unroll
      for (int c = 0; c < 4; c++) {
        const int cdx = c & 1, cdy = c >> 1;
        const int jx = ix + cdx, jy = iy + cdy;
        const float wx = cdx ? fx : 1.0f - fx;
        const float wy = cdy ? fy : 1.0f - fy;
        const bool valid = ((unsigned)jx < WS) & ((unsigned)jy < HS);
        wc[c] = valid ? a * wx * wy : 0.0f;
        const int cx = min(max(jx, 0), WS - 1);
        const int cy = min(max(jy, 0), HS - 1);
        adr[c] = hb + (unsigned)((cy << 6) + cx) * DHD;
      }
      uint4 r0[4], r1[4];
#pragma unroll
      for (int c = 0; c < 4; c++) {
        r0[c] = *(const uint4*)(value + adr[c]);
        r1[c] = *(const uint4*)(value + adr[c] + 8);
      }
#pragma unroll
      for (int c = 0; c < 4; c++) {
        bf8_fma(o0, o1, r0[c], wc[c]);
        bf8_fma(o2, o3, r1[c], wc[c]);
      }
    }
    // write FR: two swizzled uint4 (groups g = h*2+d8 hold channels k = g*8..g*8+7)
    const int llm = ll & 15;
    {
      const int off = ll * 128 + (((h * 2 + 0) ^ llm) << 3);
      uint4 st;
      st.x = ((unsigned)f2bf_rne(o0[1]) << 16) | f2bf_rne(o0[0]);
      st.y = ((unsigned)f2bf_rne(o0[3]) << 16) | f2bf_rne(o0[2]);
      st.z = ((unsigned)f2bf_rne(o1[1]) << 16) | f2bf_rne(o1[0]);
      st.w = ((unsigned)f2bf_rne(o1[3]) << 16) | f2bf_rne(o1[2]);
      *(uint4*)(FR + off) = st;
    }
    {
      const int off = ll * 128 + (((h * 2 + 1) ^ llm) << 3);
      uint4 st;
      st.x = ((unsigned)f2bf_rne(o2[1]) << 16) | f2bf_rne(o2[0]);
      st.y = ((unsigned)f2bf_rne(o2[3]) << 16) | f2bf_rne(o2[2]);
      st.z = ((unsigned)f2bf_rne(o3[1]) << 16) | f2bf_rne(o3[0]);
      st.w = ((unsigned)f2bf_rne(o3[3]) << 16) | f2bf_rne(o3[2]);
      *(uint4*)(FR + off) = st;
    }
  }
  __syncthreads();

  // ---- out GEMM: 32m x 128n, 4 waves, wave = 16m x 64n; direct float4 stores ----
  {
    const int wm = (w & 1) * 16;
    const int wn = (w >> 1) * 64;
    floatx4 acc[4];
#pragma unroll
    for (int j = 0; j < 4; j++) acc[j] = {0.0f, 0.0f, 0.0f, 0.0f};
#pragma unroll
    for (int K0 = 0; K0 < 4; K0++) {
      const int m = wm + nl;
      const int off = m * 128 + (((K0 * 4 + q) ^ (m & 15)) << 3);
      const bf16x8 ah = *(bf16x8*)(FR + off);
#pragma unroll
      for (int j = 0; j < 4; j++) {
        const int n = wn + j * 16 + nl;
        const size_t o = (size_t)(K0 * 4 + q) * CM * 8 + n * 8;
        const bf16x8 wh = *(const bf16x8*)(wf_out + o);
        const bf16x8 wl = *(const bf16x8*)(wf_out + (size_t)CM * 128 + o);
        acc[j] = __builtin_amdgcn_mfma_f32_16x16x32_bf16(ah, wl, acc[j], 0, 0, 0);
        acc[j] = __builtin_amdgcn_mfma_f32_16x16x32_bf16(ah, wh, acc[j], 0, 0, 0);
      }
    }
    // C/D: col=nl -> n, rows q*4+r -> m (contiguous in bchw) => float4 store
#pragma unroll
    for (int j = 0; j < 4; j++) {
      const int gc = wn + j * 16 + nl;
      const float bv = b_out[gc];
      float4 st = {acc[j][0] + bv, acc[j][1] + bv, acc[j][2] + bv, acc[j][3] + bv};
      *(float4*)(out + ((size_t)b * CM + gc) * LTOT + ml0 + wm + q * 4) = st;
    }
  }
}

extern "C" void kernel_launch(void* const* d_in, const int* in_sizes, int n_in,
                              void* d_out, int out_size, void* d_ws, size_t ws_size,
                              hipStream_t stream) {
  const float* nbr    = (const float*)d_in[0];
  const float* ext    = (const float*)d_in[1];
  const float* W_val  = (const float*)d_in[2];
  const float* b_val  = (const float*)d_in[3];
  const float* W_off  = (const float*)d_in[4];
  const float* b_off  = (const float*)d_in[5];
  const float* W_attn = (const float*)d_in[6];
  const float* b_attn = (const float*)d_in[7];
  const float* W_out  = (const float*)d_in[8];
  const float* b_out  = (const float*)d_in[9];
  float* out = (float*)d_out;

  unsigned short* value = (unsigned short*)d_ws;             // 8.39 MB bf16 [b][h][l][16]
  unsigned short* wf_val = value + (size_t)HB * NHEAD * LTOT * DHD;  // 64 KB
  unsigned short* wf_qa  = wf_val + 128 * 128 * 2;           // 96 KB
  unsigned short* wf_out = wf_qa + 192 * 128 * 2;            // 64 KB
  float* bias_qa = (float*)(wf_out + 128 * 128 * 2);         // 768 B

  prep<<<56, 256, 0, stream>>>(W_val, W_off, W_attn, W_out, b_off, b_attn,
                               wf_val, wf_qa, wf_out, bias_qa);
  gemm_val<<<dim3(64, HB), 256, 0, stream>>>(nbr, wf_val, b_val, value);
  samp<<<dim3(128 * HB), 256, 0, stream>>>(ext, value, wf_qa, wf_out, bias_qa, b_out, out);
}

// Round 3
// 148.908 us; speedup vs baseline: 1.8598x; 1.5585x over previous
//
#include <hip/hip_runtime.h>
#include <cstdint>

#define HB 8
#define CM 128
#define NHEAD 8
#define NPT 8
#define DHD 16
#define HS 64
#define WS 64
#define LTOT 4096
#define NQA 192   // fused off(128) + attn(64)
#define QAP 196   // qaT LDS pitch (floats): 196%32=4 -> 4-way max on float4 reads; 32*196*4=25088 B
#define LFP 132   // gemm_val transpose pitch (floats): 132%32=4 spreads banks

typedef float floatx4 __attribute__((ext_vector_type(4)));
typedef short bf16x8 __attribute__((ext_vector_type(8)));

__device__ __forceinline__ unsigned short f2bf_rne(float x) {
  unsigned u = __float_as_uint(x);
  return (unsigned short)((u + 0x7FFFu + ((u >> 16) & 1)) >> 16);
}
__device__ __forceinline__ void split_bf(float x, unsigned short& h, unsigned short& l) {
  unsigned u = __float_as_uint(x);
  h = (unsigned short)(u >> 16);
  float r = x - __uint_as_float(u & 0xFFFF0000u);
  l = (unsigned short)(__float_as_uint(r) >> 16);
}
__device__ __forceinline__ float fast_tanh(float x) {
  float e = __expf(2.0f * x);
  return 1.0f - 2.0f / (e + 1.0f);
}
// unpack uint4 (8 bf16) -> 2x floatx4, fused multiply-accumulate by scalar wc
__device__ __forceinline__ void bf8_fma(floatx4& oa, floatx4& ob, const uint4 r, const float wc) {
  floatx4 va = {__uint_as_float(r.x << 16), __uint_as_float(r.x & 0xFFFF0000u),
                __uint_as_float(r.y << 16), __uint_as_float(r.y & 0xFFFF0000u)};
  floatx4 vb = {__uint_as_float(r.z << 16), __uint_as_float(r.z & 0xFFFF0000u),
                __uint_as_float(r.w << 16), __uint_as_float(r.w & 0xFFFF0000u)};
  oa += va * wc;
  ob += vb * wc;
}

// Weight prep -> bf16 hi/lo fragment layout: element (n,k) at (k>>3)*Nn*8 + n*8 + (k&7).
__global__ __launch_bounds__(256) void prep(const float* __restrict__ Wv,
                                            const float* __restrict__ Wo,
                                            const float* __restrict__ Wa,
                                            const float* __restrict__ Ww,
                                            const float* __restrict__ bo,
                                            const float* __restrict__ ba,
                                            unsigned short* __restrict__ wf_val,
                                            unsigned short* __restrict__ wf_qa,
                                            unsigned short* __restrict__ wf_out,
                                            float* __restrict__ bias_qa) {
  const int gid = blockIdx.x * 256 + threadIdx.x;  // 14336 = 32 k4 * 448 n
  const int k4 = gid / 448;
  const int ng = gid - k4 * 448;

  const float* src;
  unsigned short* dst;
  int Nsrc, Nn, nd, n;
  if (ng < 128) {        src = Wv; dst = wf_val; Nsrc = 128; Nn = 128; n = ng;        nd = n; }
  else if (ng < 256) {   src = Wo; dst = wf_qa;  Nsrc = 128; Nn = 192; n = ng - 128;  nd = n; }
  else if (ng < 320) {   src = Wa; dst = wf_qa;  Nsrc = 64;  Nn = 192; n = ng - 256;  nd = n + 128; }
  else {                 src = Ww; dst = wf_out; Nsrc = 128; Nn = 128; n = ng - 320;  nd = n; }

  ushort4 hi, lo;
  split_bf(src[(k4 * 4 + 0) * Nsrc + n], hi.x, lo.x);
  split_bf(src[(k4 * 4 + 1) * Nsrc + n], hi.y, lo.y);
  split_bf(src[(k4 * 4 + 2) * Nsrc + n], hi.z, lo.z);
  split_bf(src[(k4 * 4 + 3) * Nsrc + n], hi.w, lo.w);
  const int off = (k4 >> 1) * Nn * 8 + nd * 8 + (k4 & 1) * 4;
  *(ushort4*)(dst + off) = hi;
  *(ushort4*)(dst + Nn * 128 + off) = lo;

  if (gid < 128) bias_qa[gid] = bo[gid];
  else if (gid < 192) bias_qa[gid] = ba[gid - 128];
}

// K1: value projection. Tile 64 m x 128 n, 256 thr (4 waves, wave = 32m x 64n).
// 3-term bf16 split. Epilogue: LDS transpose -> COALESCED uint4 bf16 stores.
__global__ __launch_bounds__(256, 4) void gemm_val(const float* __restrict__ nbr,
                                                   const unsigned short* __restrict__ WF,
                                                   const float* __restrict__ bias,
                                                   unsigned short* __restrict__ value) {
  __shared__ __align__(16) char smem[33792];   // staging 32768; transpose 64*132*4=33792
  unsigned short* AB = (unsigned short*)smem;  // hi [64][128]; lo at +8192 us
  const int t = threadIdx.x;
  const int ml0 = blockIdx.x * 64;
  const int b = blockIdx.y;

  {
    const float* src = nbr + (size_t)b * CM * LTOT + ml0;
    const int x = t & 63, kq = t >> 6;
#pragma unroll
    for (int i = 0; i < 8; i++) {
      const int kb = kq * 4 + i * 16;
      ushort4 hi, lo;
      split_bf(src[(size_t)(kb + 0) * LTOT + x], hi.x, lo.x);
      split_bf(src[(size_t)(kb + 1) * LTOT + x], hi.y, lo.y);
      split_bf(src[(size_t)(kb + 2) * LTOT + x], hi.z, lo.z);
      split_bf(src[(size_t)(kb + 3) * LTOT + x], hi.w, lo.w);
      const int off = x * 128 + (((kb >> 3) ^ (x & 15)) << 3) + (kb & 7);
      *(ushort4*)(AB + off) = hi;
      *(ushort4*)(AB + 8192 + off) = lo;
    }
  }
  __syncthreads();

  const int w = t >> 6, lane = t & 63;
  const int wm = (w >> 1) * 32, wn = (w & 1) * 64;
  const int nl = lane & 15, q = lane >> 4;

  floatx4 acc[2][4];
#pragma unroll
  for (int mt = 0; mt < 2; mt++)
#pragma unroll
    for (int j = 0; j < 4; j++) acc[mt][j] = {0.0f, 0.0f, 0.0f, 0.0f};

#pragma unroll
  for (int K0 = 0; K0 < 4; K0++) {
    bf16x8 ah[2], al[2];
#pragma unroll
    for (int mt = 0; mt < 2; mt++) {
      const int m = wm + mt * 16 + nl;
      const int off = m * 128 + (((K0 * 4 + q) ^ (m & 15)) << 3);
      ah[mt] = *(bf16x8*)(AB + off);
      al[mt] = *(bf16x8*)(AB + 8192 + off);
    }
#pragma unroll
    for (int j = 0; j < 4; j++) {
      const size_t o = (size_t)(K0 * 4 + q) * CM * 8 + (wn + j * 16 + nl) * 8;
      const bf16x8 wh = *(const bf16x8*)(WF + o);
      const bf16x8 wl = *(const bf16x8*)(WF + (size_t)CM * 128 + o);
#pragma unroll
      for (int mt = 0; mt < 2; mt++) {
        acc[mt][j] = __builtin_amdgcn_mfma_f32_16x16x32_bf16(al[mt], wh, acc[mt][j], 0, 0, 0);
        acc[mt][j] = __builtin_amdgcn_mfma_f32_16x16x32_bf16(ah[mt], wl, acc[mt][j], 0, 0, 0);
        acc[mt][j] = __builtin_amdgcn_mfma_f32_16x16x32_bf16(ah[mt], wh, acc[mt][j], 0, 0, 0);
      }
    }
  }

  // ---- epilogue: acc -> LDS [64 l][132] fp32 -> packed bf16 uint4 coalesced stores ----
  __syncthreads();  // AB dead
  float* LF = (float*)smem;
#pragma unroll
  for (int j = 0; j < 4; j++) {
    const int gc = wn + j * 16 + nl;
    const float bv = bias[gc];
#pragma unroll
    for (int mt = 0; mt < 2; mt++)
#pragma unroll
      for (int r = 0; r < 4; r++)
        LF[(wm + mt * 16 + q * 4 + r) * LFP + gc] = acc[mt][j][r] + bv;
  }
  __syncthreads();
  // 1024 uint4 chunks: c = h(3b) | l(6b) | half(1b); wave writes contiguous 1 KB per h
#pragma unroll
  for (int i = 0; i < 4; i++) {
    const int c = t + i * 256;
    const int h = c >> 7, rem = c & 127, l = rem >> 1, half = rem & 1;
    const float* sp = LF + l * LFP + h * 16 + half * 8;
    uint4 st;
    st.x = ((unsigned)f2bf_rne(sp[1]) << 16) | f2bf_rne(sp[0]);
    st.y = ((unsigned)f2bf_rne(sp[3]) << 16) | f2bf_rne(sp[2]);
    st.z = ((unsigned)f2bf_rne(sp[5]) << 16) | f2bf_rne(sp[4]);
    st.w = ((unsigned)f2bf_rne(sp[7]) << 16) | f2bf_rne(sp[6]);
    *(uint4*)(value + ((size_t)(b * NHEAD + h) * LTOT + ml0 + l) * DHD + half * 8) = st;
  }
}

// K2: per 32-l tile: stage ext -> qa GEMM -> sampling params in REGISTERS ->
// full-dh gather (thread = one (ll,h), 32B/corner via 2x uint4) -> out GEMM.
// LDS phases overlap at offset 0: AB(16K) / qaT(25088) / FR(8K) -> 25088 B total.
// launch_bounds(256,2): with MFMA present the backend splits the unified VGPR file
// arch/acc at HALF the waves-per-EU budget -> (256,5)=>48 arch, (256,4)=>64 arch,
// both spilled (~200-450 MB scratch HBM). Budget 256 -> 128 arch >= ~90 needed.
__global__ __launch_bounds__(256, 2) void samp(const float* __restrict__ ext,
                                               const unsigned short* __restrict__ value,
                                               const unsigned short* __restrict__ wf_qa,
                                               const unsigned short* __restrict__ wf_out,
                                               const float* __restrict__ bias_qa,
                                               const float* __restrict__ b_out,
                                               float* __restrict__ out) {
  __shared__ __align__(16) char smem[25088];
  unsigned short* AB = (unsigned short*)smem;  // [32][128] hi; lo at +4096 us (16384 B)
  float* qaT = (float*)smem;                   // [32][QAP] = 25088 B (after AB dead)
  unsigned short* FR = (unsigned short*)smem;  // [32][128] bf16 = 8192 B (after qaT dead)

  const int t = threadIdx.x;
  const int b = blockIdx.x & 7;                // XCD affinity
  const int ml0 = (blockIdx.x >> 3) * 32;
  const int w = t >> 6, lane = t & 63;
  const int nl = lane & 15, q = lane >> 4;

  // ---- stage ext 32-l tile (fp32 -> bf16 hi/lo, swizzled) ----
  {
    const float* src = ext + (size_t)b * CM * LTOT + ml0;
    const int x = t & 31, kq = t >> 5;  // kq 0..7
#pragma unroll
    for (int i = 0; i < 4; i++) {
      const int kb = i * 32 + kq * 4;
      ushort4 hi, lo;
      split_bf(src[(size_t)(kb + 0) * LTOT + x], hi.x, lo.x);
      split_bf(src[(size_t)(kb + 1) * LTOT + x], hi.y, lo.y);
      split_bf(src[(size_t)(kb + 2) * LTOT + x], hi.z, lo.z);
      split_bf(src[(size_t)(kb + 3) * LTOT + x], hi.w, lo.w);
      const int off = x * 128 + (((kb >> 3) ^ (x & 15)) << 3) + (kb & 7);
      *(ushort4*)(AB + off) = hi;
      *(ushort4*)(AB + 4096 + off) = lo;
    }
  }
  __syncthreads();

  // ---- qa GEMM: 32m x 192n, 4 waves, wave = 16m x 96n; result -> qaT (LDS, overlaps AB) ----
  {
    const int wm = (w & 1) * 16;
    const int wn = (w >> 1) * 96;
    floatx4 acc[6];
#pragma unroll
    for (int j = 0; j < 6; j++) acc[j] = {0.0f, 0.0f, 0.0f, 0.0f};
#pragma unroll
    for (int K0 = 0; K0 < 4; K0++) {
      const int m = wm + nl;
      const int off = m * 128 + (((K0 * 4 + q) ^ (m & 15)) << 3);
      const bf16x8 ah = *(bf16x8*)(AB + off);
      const bf16x8 al = *(bf16x8*)(AB + 4096 + off);
#pragma unroll
      for (int j = 0; j < 6; j++) {
        const size_t o = (size_t)(K0 * 4 + q) * NQA * 8 + (wn + j * 16 + nl) * 8;
        const bf16x8 wh = *(const bf16x8*)(wf_qa + o);
        const bf16x8 wl = *(const bf16x8*)(wf_qa + (size_t)NQA * 128 + o);
        acc[j] = __builtin_amdgcn_mfma_f32_16x16x32_bf16(al, wh, acc[j], 0, 0, 0);
        acc[j] = __builtin_amdgcn_mfma_f32_16x16x32_bf16(ah, wl, acc[j], 0, 0, 0);
        acc[j] = __builtin_amdgcn_mfma_f32_16x16x32_bf16(ah, wh, acc[j], 0, 0, 0);
      }
    }
    __syncthreads();  // all AB reads done -> qaT may overwrite
#pragma unroll
    for (int j = 0; j < 6; j++) {
      const int n = wn + j * 16 + nl;
      const float bv = bias_qa[n];
#pragma unroll
      for (int r = 0; r < 4; r++)
        qaT[(wm + q * 4 + r) * QAP + n] = acc[j][r] + bv;
    }
  }
  __syncthreads();

  // ---- sampling params -> REGISTERS; thread t = (ll = t>>3, h = t&7), same as gather ----
  float px[8], py[8], aw[8];
  const int ll = t >> 3, h = t & 7;
  {
    const float* qrow = qaT + ll * QAP;
    float4 of[4];
#pragma unroll
    for (int j = 0; j < 4; j++) of[j] = *(const float4*)(qrow + h * 16 + j * 4);
    const float4 lga = *(const float4*)(qrow + 128 + h * 8);
    const float4 lgb = *(const float4*)(qrow + 128 + h * 8 + 4);
    const float lg[8] = {lga.x, lga.y, lga.z, lga.w, lgb.x, lgb.y, lgb.z, lgb.w};
    float m = lg[0];
#pragma unroll
    for (int p = 1; p < 8; p++) m = fmaxf(m, lg[p]);
    float e[8], s = 0.0f;
#pragma unroll
    for (int p = 0; p < 8; p++) { e[p] = __expf(lg[p] - m); s += e[p]; }
    const float inv = 1.0f / s;
    const int l = ml0 + ll;
    const float xf = (float)(l & (WS - 1));
    const float yf = (float)(l >> 6);
#pragma unroll
    for (int p = 0; p < 8; p++) {
      const float ox = (p & 1) ? of[p >> 1].z : of[p >> 1].x;
      const float oy = (p & 1) ? of[p >> 1].w : of[p >> 1].y;
      px[p] = xf + 10.0f * fast_tanh(ox);
      py[p] = yf + 10.0f * fast_tanh(oy);
      aw[p] = e[p] * inv;
    }
  }
  __syncthreads();  // qaT dead -> FR may be written

  // ---- gather: thread owns full dh=16 of one (ll,h); 32B per corner (2x uint4) ----
  {
    const unsigned hb = (unsigned)(b * NHEAD + h) * LTOT * DHD;  // us offset of head plane
    floatx4 o0 = {0.f, 0.f, 0.f, 0.f}, o1 = o0, o2 = o0, o3 = o0;
#pragma unroll
    for (int p = 0; p < 8; p++) {
      const float x0f = floorf(px[p]), y0f = floorf(py[p]);
      const float fx = px[p] - x0f, fy = py[p] - y0f;
      const int ix = (int)x0f, iy = (int)y0f;
      const float a = aw[p];
      float wc[4];
      unsigned adr[4];
#pragma unroll
      for (int c = 0; c < 4; c++) {
        const int cdx = c & 1, cdy = c >> 1;
        const int jx = ix + cdx, jy = iy + cdy;
        const float wx = cdx ? fx : 1.0f - fx;
        const float wy = cdy ? fy : 1.0f - fy;
        const bool valid = ((unsigned)jx < WS) & ((unsigned)jy < HS);
        wc[c] = valid ? a * wx * wy : 0.0f;
        const int cx = min(max(jx, 0), WS - 1);
        const int cy = min(max(jy, 0), HS - 1);
        adr[c] = hb + (unsigned)((cy << 6) + cx) * DHD;
      }
      uint4 r0[4], r1[4];
#pragma unroll
      for (int c = 0; c < 4; c++) {
        r0[c] = *(const uint4*)(value + adr[c]);
        r1[c] = *(const uint4*)(value + adr[c] + 8);
      }
#pragma unroll
      for (int c = 0; c < 4; c++) {
        bf8_fma(o0, o1, r0[c], wc[c]);
        bf8_fma(o2, o3, r1[c], wc[c]);
      }
    }
    // write FR: two swizzled uint4 (groups g = h*2+d8 hold channels k = g*8..g*8+7)
    const int llm = ll & 15;
    {
      const int off = ll * 128 + (((h * 2 + 0) ^ llm) << 3);
      uint4 st;
      st.x = ((unsigned)f2bf_rne(o0[1]) << 16) | f2bf_rne(o0[0]);
      st.y = ((unsigned)f2bf_rne(o0[3]) << 16) | f2bf_rne(o0[2]);
      st.z = ((unsigned)f2bf_rne(o1[1]) << 16) | f2bf_rne(o1[0]);
      st.w = ((unsigned)f2bf_rne(o1[3]) << 16) | f2bf_rne(o1[2]);
      *(uint4*)(FR + off) = st;
    }
    {
      const int off = ll * 128 + (((h * 2 + 1) ^ llm) << 3);
      uint4 st;
      st.x = ((unsigned)f2bf_rne(o2[1]) << 16) | f2bf_rne(o2[0]);
      st.y = ((unsigned)f2bf_rne(o2[3]) << 16) | f2bf_rne(o2[2]);
      st.z = ((unsigned)f2bf_rne(o3[1]) << 16) | f2bf_rne(o3[0]);
      st.w = ((unsigned)f2bf_rne(o3[3]) << 16) | f2bf_rne(o3[2]);
      *(uint4*)(FR + off) = st;
    }
  }
  __syncthreads();

  // ---- out GEMM: 32m x 128n, 4 waves, wave = 16m x 64n; direct float4 stores ----
  {
    const int wm = (w & 1) * 16;
    const int wn = (w >> 1) * 64;
    floatx4 acc[4];
#pragma unroll
    for (int j = 0; j < 4; j++) acc[j] = {0.0f, 0.0f, 0.0f, 0.0f};
#pragma unroll
    for (int K0 = 0; K0 < 4; K0++) {
      const int m = wm + nl;
      const int off = m * 128 + (((K0 * 4 + q) ^ (m & 15)) << 3);
      const bf16x8 ah = *(bf16x8*)(FR + off);
#pragma unroll
      for (int j = 0; j < 4; j++) {
        const int n = wn + j * 16 + nl;
        const size_t o = (size_t)(K0 * 4 + q) * CM * 8 + n * 8;
        const bf16x8 wh = *(const bf16x8*)(wf_out + o);
        const bf16x8 wl = *(const bf16x8*)(wf_out + (size_t)CM * 128 + o);
        acc[j] = __builtin_amdgcn_mfma_f32_16x16x32_bf16(ah, wl, acc[j], 0, 0, 0);
        acc[j] = __builtin_amdgcn_mfma_f32_16x16x32_bf16(ah, wh, acc[j], 0, 0, 0);
      }
    }
    // C/D: col=nl -> n, rows q*4+r -> m (contiguous in bchw) => float4 store
#pragma unroll
    for (int j = 0; j < 4; j++) {
      const int gc = wn + j * 16 + nl;
      const float bv = b_out[gc];
      float4 st = {acc[j][0] + bv, acc[j][1] + bv, acc[j][2] + bv, acc[j][3] + bv};
      *(float4*)(out + ((size_t)b * CM + gc) * LTOT + ml0 + wm + q * 4) = st;
    }
  }
}

extern "C" void kernel_launch(void* const* d_in, const int* in_sizes, int n_in,
                              void* d_out, int out_size, void* d_ws, size_t ws_size,
                              hipStream_t stream) {
  const float* nbr    = (const float*)d_in[0];
  const float* ext    = (const float*)d_in[1];
  const float* W_val  = (const float*)d_in[2];
  const float* b_val  = (const float*)d_in[3];
  const float* W_off  = (const float*)d_in[4];
  const float* b_off  = (const float*)d_in[5];
  const float* W_attn = (const float*)d_in[6];
  const float* b_attn = (const float*)d_in[7];
  const float* W_out  = (const float*)d_in[8];
  const float* b_out  = (const float*)d_in[9];
  float* out = (float*)d_out;

  unsigned short* value = (unsigned short*)d_ws;             // 8.39 MB bf16 [b][h][l][16]
  unsigned short* wf_val = value + (size_t)HB * NHEAD * LTOT * DHD;  // 64 KB
  unsigned short* wf_qa  = wf_val + 128 * 128 * 2;           // 96 KB
  unsigned short* wf_out = wf_qa + 192 * 128 * 2;            // 64 KB
  float* bias_qa = (float*)(wf_out + 128 * 128 * 2);         // 768 B

  prep<<<56, 256, 0, stream>>>(W_val, W_off, W_attn, W_out, b_off, b_attn,
                               wf_val, wf_qa, wf_out, bias_qa);
  gemm_val<<<dim3(64, HB), 256, 0, stream>>>(nbr, wf_val, b_val, value);
  samp<<<dim3(128 * HB), 256, 0, stream>>>(ext, value, wf_qa, wf_out, bias_qa, b_out, out);
}